// Round 2
// baseline (4503.392 us; speedup 1.0000x reference)
//
#include <hip/hip_runtime.h>
#include <hip/hip_bf16.h>

// Problem: ALiBi MHA. B=2,T=2048,D=1024,H=16,DK=64.
// Round 2: same correctness-first pipeline as R1, but inputs/output are fp32
// (per reference dtypes; R1's NaN is the signature of reading fp32 as bf16).

#define B_  2
#define T_  2048
#define D_  1024
#define H_  16
#define DK_ 64
#define M_  (B_ * T_)   // 4096 rows for the projection GEMMs

using in_t = float;    // flip to __hip_bfloat16 if dtype theory is wrong
using out_t = float;

__device__ __forceinline__ float to_f(float x) { return x; }
__device__ __forceinline__ float to_f(__hip_bfloat16 x) { return __bfloat162float(x); }
__device__ __forceinline__ void store_out(float* p, float v) { *p = v; }
__device__ __forceinline__ void store_out(__hip_bfloat16* p, float v) { *p = __float2bfloat16(v); }

// C = X @ W^T  (X: [M,K] row-major, W: [N,K] row-major)
// MODE 0: write fp32 to split-head layout [B,H,T,DK] (n = h*DK+dk, m = b*T+t)
// MODE 1: write out_t row-major [M,N], adding bias[n]
template <typename TX, int MODE>
__global__ __launch_bounds__(256) void gemm_xwt(const TX* __restrict__ X,
                                                const in_t* __restrict__ W,
                                                const in_t* __restrict__ bias,
                                                float* __restrict__ outf,
                                                out_t* __restrict__ outb,
                                                int M, int N, int K) {
    __shared__ float As[16][65];  // [k][m], padded
    __shared__ float Bs[16][65];  // [k][n], padded
    const int tid = threadIdx.x;
    const int tx = tid & 15;      // 0..15 -> n-quad
    const int ty = tid >> 4;      // 0..15 -> m-quad
    const int m0 = blockIdx.y * 64;
    const int n0 = blockIdx.x * 64;

    float acc[4][4] = {};

    for (int k0 = 0; k0 < K; k0 += 16) {
#pragma unroll
        for (int it = 0; it < 4; ++it) {
            int r = ty + it * 16;  // 0..63
            int c = tx;            // 0..15
            As[c][r] = to_f(X[(size_t)(m0 + r) * K + k0 + c]);
            Bs[c][r] = to_f(W[(size_t)(n0 + r) * K + k0 + c]);
        }
        __syncthreads();
#pragma unroll
        for (int kk = 0; kk < 16; ++kk) {
            float a[4], b[4];
#pragma unroll
            for (int i = 0; i < 4; ++i) a[i] = As[kk][ty * 4 + i];
#pragma unroll
            for (int j = 0; j < 4; ++j) b[j] = Bs[kk][tx * 4 + j];
#pragma unroll
            for (int i = 0; i < 4; ++i)
#pragma unroll
                for (int j = 0; j < 4; ++j) acc[i][j] += a[i] * b[j];
        }
        __syncthreads();
    }

#pragma unroll
    for (int i = 0; i < 4; ++i) {
        int m = m0 + ty * 4 + i;
        int b_ = m / T_;
        int t_ = m % T_;
#pragma unroll
        for (int j = 0; j < 4; ++j) {
            int n = n0 + tx * 4 + j;
            if (MODE == 0) {
                int h = n / DK_, dk = n % DK_;
                outf[(((size_t)b_ * H_ + h) * T_ + t_) * DK_ + dk] = acc[i][j];
            } else {
                float v = acc[i][j] + to_f(bias[n]);
                store_out(&outb[(size_t)m * N + n], v);
            }
        }
    }
}

// One block (256 threads) per (query row i, b*H+h).
// Q/K/V fp32 [B,H,T,DK]; alibi in_t [H,T,T]; ctx fp32 [B,T,D].
__global__ __launch_bounds__(256) void attn_kernel(const float* __restrict__ Q,
                                                   const float* __restrict__ K,
                                                   const float* __restrict__ V,
                                                   const in_t* __restrict__ alibi,
                                                   float* __restrict__ ctx) {
    const int i  = blockIdx.x;           // query row
    const int bh = blockIdx.y;           // b*H + h
    const int b  = bh / H_;
    const int h  = bh % H_;
    const int tid = threadIdx.x;

    __shared__ float q[DK_];
    __shared__ float sc[T_];             // 8 KB scores
    __shared__ float red[256];

    const float* Qr = Q + ((size_t)bh * T_ + i) * DK_;
    const float* Kb = K + (size_t)bh * T_ * DK_;
    const float* Vb = V + (size_t)bh * T_ * DK_;
    const in_t* ab = alibi + ((size_t)h * T_ + i) * T_;

    if (tid < DK_) q[tid] = Qr[tid];
    __syncthreads();

    // pass 1: scores + local max
    float lmax = -INFINITY;
    for (int j = tid; j <= i; j += 256) {
        const float* kr = Kb + (size_t)j * DK_;
        float s = 0.f;
#pragma unroll
        for (int d = 0; d < DK_; ++d) s += q[d] * kr[d];
        s = s * 0.125f + to_f(ab[j]);
        sc[j] = s;
        lmax = fmaxf(lmax, s);
    }
    red[tid] = lmax;
    __syncthreads();
    for (int s = 128; s > 0; s >>= 1) {
        if (tid < s) red[tid] = fmaxf(red[tid], red[tid + s]);
        __syncthreads();
    }
    const float mx = red[0];
    __syncthreads();

    // pass 2: exp + sum
    float lsum = 0.f;
    for (int j = tid; j <= i; j += 256) {
        float p = __expf(sc[j] - mx);
        sc[j] = p;
        lsum += p;
    }
    red[tid] = lsum;
    __syncthreads();
    for (int s = 128; s > 0; s >>= 1) {
        if (tid < s) red[tid] += red[tid + s];
        __syncthreads();
    }
    const float inv = 1.0f / red[0];
    __syncthreads();   // everyone has read red[0] before we reuse red

    // pass 3: out[d] = sum_j p_j * V[j][d]; 4 groups x 64 dims
    const int d = tid & 63;
    const int g = tid >> 6;
    float acc = 0.f;
    for (int j = g; j <= i; j += 4) acc += sc[j] * Vb[(size_t)j * DK_ + d];
    red[g * 64 + d] = acc;
    __syncthreads();
    if (tid < DK_) {
        float o = (red[tid] + red[64 + tid] + red[128 + tid] + red[192 + tid]) * inv;
        ctx[((size_t)b * T_ + i) * D_ + h * DK_ + tid] = o;
    }
}

extern "C" void kernel_launch(void* const* d_in, const int* in_sizes, int n_in,
                              void* d_out, int out_size, void* d_ws, size_t ws_size,
                              hipStream_t stream) {
    const in_t* query = (const in_t*)d_in[0];
    const in_t* key   = (const in_t*)d_in[1];
    const in_t* value = (const in_t*)d_in[2];
    const in_t* alibi = (const in_t*)d_in[3];
    const in_t* Wq    = (const in_t*)d_in[4];
    const in_t* Wk    = (const in_t*)d_in[5];
    const in_t* Wv    = (const in_t*)d_in[6];
    const in_t* Wo    = (const in_t*)d_in[7];
    const in_t* bo    = (const in_t*)d_in[8];
    out_t* out = (out_t*)d_out;

    const size_t elems = (size_t)B_ * H_ * T_ * DK_;  // 4M
    float* Qws   = (float*)d_ws;
    float* Kws   = Qws + elems;
    float* Vws   = Kws + elems;
    float* ctxws = Vws + elems;   // [B,T,D] fp32; total 64 MB

    dim3 gGemm(D_ / 64, M_ / 64);  // (16, 64)
    dim3 blk(256);

    gemm_xwt<in_t, 0><<<gGemm, blk, 0, stream>>>(query, Wq, nullptr, Qws, nullptr, M_, D_, D_);
    gemm_xwt<in_t, 0><<<gGemm, blk, 0, stream>>>(key,   Wk, nullptr, Kws, nullptr, M_, D_, D_);
    gemm_xwt<in_t, 0><<<gGemm, blk, 0, stream>>>(value, Wv, nullptr, Vws, nullptr, M_, D_, D_);

    dim3 gAttn(T_, B_ * H_);  // (2048, 32)
    attn_kernel<<<gAttn, blk, 0, stream>>>(Qws, Kws, Vws, alibi, ctxws);

    gemm_xwt<float, 1><<<gGemm, blk, 0, stream>>>(ctxws, Wo, bo, nullptr, out, M_, D_, D_);
}

// Round 3
// 1233.342 us; speedup vs baseline: 3.6514x; 3.6514x over previous
//
#include <hip/hip_runtime.h>
#include <hip/hip_bf16.h>

// ALiBi MHA. B=2,T=2048,D=1024,H=16,DK=64. fp32 in/out.
// R3: flash-style MFMA bf16 attention + inline alibi; projections emit bf16
// (Q,K row-major split-head; V transposed [bh][DK][T]); GEMMs still fp32 VALU.

#define B_  2
#define T_  2048
#define D_  1024
#define H_  16
#define DK_ 64
#define M_  (B_ * T_)

typedef unsigned short u16;
typedef __attribute__((ext_vector_type(8))) short bf16x8;
typedef __attribute__((ext_vector_type(4))) float f32x4;

// slope_h = 2^(-(h+1)/2), double literals -> fp32 (bit-exact vs numpy)
__device__ __constant__ float d_slopes[16] = {
    0.70710678118654752440f, 0.5f, 0.35355339059327376220f, 0.25f,
    0.17677669529663688110f, 0.125f, 0.088388347648318440550f, 0.0625f,
    0.044194173824159220275f, 0.03125f, 0.022097086912079610137f, 0.015625f,
    0.011048543456039805068f, 0.0078125f, 0.0055242717280199025342f, 0.00390625f};

__device__ __forceinline__ float to_f(float x) { return x; }
__device__ __forceinline__ float to_f(__hip_bfloat16 x) { return __bfloat162float(x); }
__device__ __forceinline__ u16 f2bf_bits(float v) {
    __hip_bfloat16 h = __float2bfloat16(v);
    return *reinterpret_cast<u16*>(&h);
}

// C = X @ W^T  (X: [M,K] row-major TX, W: [N,K] row-major fp32)
// MODE 0: bf16 split-head [bh][T][DK]   (Q, K)
// MODE 2: bf16 transposed [bh][DK][T]   (V^T)
// MODE 1: fp32 row-major [M,N] + bias   (output projection)
template <typename TX, int MODE>
__global__ __launch_bounds__(256) void gemm_xwt(const TX* __restrict__ X,
                                                const float* __restrict__ W,
                                                const float* __restrict__ bias,
                                                u16* __restrict__ outq,
                                                float* __restrict__ outf,
                                                int M, int N, int K) {
    __shared__ float As[16][65];
    __shared__ float Bs[16][65];
    const int tid = threadIdx.x;
    const int tx = tid & 15;
    const int ty = tid >> 4;
    const int m0 = blockIdx.y * 64;
    const int n0 = blockIdx.x * 64;

    float acc[4][4] = {};

    for (int k0 = 0; k0 < K; k0 += 16) {
#pragma unroll
        for (int it = 0; it < 4; ++it) {
            int r = ty + it * 16;
            int c = tx;
            As[c][r] = to_f(X[(size_t)(m0 + r) * K + k0 + c]);
            Bs[c][r] = W[(size_t)(n0 + r) * K + k0 + c];
        }
        __syncthreads();
#pragma unroll
        for (int kk = 0; kk < 16; ++kk) {
            float a[4], b[4];
#pragma unroll
            for (int i = 0; i < 4; ++i) a[i] = As[kk][ty * 4 + i];
#pragma unroll
            for (int j = 0; j < 4; ++j) b[j] = Bs[kk][tx * 4 + j];
#pragma unroll
            for (int i = 0; i < 4; ++i)
#pragma unroll
                for (int j = 0; j < 4; ++j) acc[i][j] += a[i] * b[j];
        }
        __syncthreads();
    }

#pragma unroll
    for (int i = 0; i < 4; ++i) {
        int m = m0 + ty * 4 + i;
        int b_ = m / T_;
        int t_ = m % T_;
#pragma unroll
        for (int j = 0; j < 4; ++j) {
            int n = n0 + tx * 4 + j;
            if (MODE == 0) {
                int h = n / DK_, dk = n % DK_;
                outq[(((size_t)b_ * H_ + h) * T_ + t_) * DK_ + dk] = f2bf_bits(acc[i][j]);
            } else if (MODE == 2) {
                int h = n / DK_, dk = n % DK_;
                outq[(((size_t)b_ * H_ + h) * DK_ + dk) * T_ + t_] = f2bf_bits(acc[i][j]);
            } else {
                outf[(size_t)m * N + n] = acc[i][j] + bias[n];
            }
        }
    }
}

// Flash attention: 4 waves/block, wave w handles Q rows qb..qb+15 of one bh.
// Q,K: bf16 [bh][T][DK]; VT: bf16 [bh][DK][T]; ctx out: bf16 [B][T][D].
__global__ __launch_bounds__(256) void flash_attn(const u16* __restrict__ Q,
                                                  const u16* __restrict__ K,
                                                  const u16* __restrict__ VT,
                                                  u16* __restrict__ ctx) {
    const int bh = blockIdx.y;
    const int b  = bh >> 4;
    const int h  = bh & 15;
    const int wave = threadIdx.x >> 6;
    const int lane = threadIdx.x & 63;
    const int l15 = lane & 15;
    const int quad = lane >> 4;
    const int qb = blockIdx.x * 64 + wave * 16;
    const float slope = d_slopes[h];

    // per-wave P buffer: 16 rows x 32 cols, stride 40 u16 (80 B: 16-B aligned,
    // quad write offset = 80 dwords -> +16 banks -> 2-way (free))
    __shared__ u16 plds[4][16 * 40];
    u16* pl = plds[wave];

    const size_t baseQK = (size_t)bh * T_ * DK_;
    const u16* qptr = Q + baseQK + (size_t)(qb + l15) * DK_ + quad * 8;
    bf16x8 aq0 = *(const bf16x8*)qptr;
    bf16x8 aq1 = *(const bf16x8*)(qptr + 32);

    f32x4 o[4];
    float m[4], l[4];
#pragma unroll
    for (int r = 0; r < 4; ++r) {
        o[r] = f32x4{0.f, 0.f, 0.f, 0.f};
        m[r] = -INFINITY;
        l[r] = 0.f;
    }

    const f32x4 zero = {0.f, 0.f, 0.f, 0.f};

    for (int kb = 0; kb <= qb + 15; kb += 32) {
        // K fragments: B[k=d][n=kcol]; lane holds K[kb + (tile*16) + l15][quad*8 + j]
        const u16* kptr = K + baseQK + (size_t)(kb + l15) * DK_ + quad * 8;
        bf16x8 bk00 = *(const bf16x8*)kptr;
        bf16x8 bk01 = *(const bf16x8*)(kptr + 32);
        bf16x8 bk10 = *(const bf16x8*)(kptr + 16 * DK_);
        bf16x8 bk11 = *(const bf16x8*)(kptr + 16 * DK_ + 32);

        f32x4 s0 = __builtin_amdgcn_mfma_f32_16x16x32_bf16(aq0, bk00, zero, 0, 0, 0);
        s0 = __builtin_amdgcn_mfma_f32_16x16x32_bf16(aq1, bk01, s0, 0, 0, 0);
        f32x4 s1 = __builtin_amdgcn_mfma_f32_16x16x32_bf16(aq0, bk10, zero, 0, 0, 0);
        s1 = __builtin_amdgcn_mfma_f32_16x16x32_bf16(aq1, bk11, s1, 0, 0, 0);

        // scale + alibi + causal mask. C-layout: row=quad*4+r, col=l15 (+16 for s1)
        float sc0[4], sc1[4];
#pragma unroll
        for (int r = 0; r < 4; ++r) {
            const int row = qb + quad * 4 + r;
            const int c0 = kb + l15;
            const int c1 = c0 + 16;
            float v0 = s0[r] * 0.125f + slope * (float)(c0 - row);
            float v1 = s1[r] * 0.125f + slope * (float)(c1 - row);
            sc0[r] = (c0 <= row) ? v0 : -INFINITY;
            sc1[r] = (c1 <= row) ? v1 : -INFINITY;
        }

        // online softmax per row (reduce across the 16 col-lanes)
        float alpha[4];
#pragma unroll
        for (int r = 0; r < 4; ++r) {
            float t = fmaxf(sc0[r], sc1[r]);
            t = fmaxf(t, __shfl_xor(t, 1));
            t = fmaxf(t, __shfl_xor(t, 2));
            t = fmaxf(t, __shfl_xor(t, 4));
            t = fmaxf(t, __shfl_xor(t, 8));
            const float mn = fmaxf(m[r], t);
            alpha[r] = __expf(m[r] - mn);
            m[r] = mn;
            const float p0 = __expf(sc0[r] - mn);
            const float p1 = __expf(sc1[r] - mn);
            pl[(quad * 4 + r) * 40 + l15]      = f2bf_bits(p0);
            pl[(quad * 4 + r) * 40 + l15 + 16] = f2bf_bits(p1);
            float s = p0 + p1;
            s += __shfl_xor(s, 1);
            s += __shfl_xor(s, 2);
            s += __shfl_xor(s, 4);
            s += __shfl_xor(s, 8);
            l[r] = l[r] * alpha[r] + s;
        }

#pragma unroll
        for (int t = 0; t < 4; ++t)
#pragma unroll
            for (int r = 0; r < 4; ++r) o[t][r] *= alpha[r];

        // P: C-layout -> A-layout via LDS (same-wave, in-order LDS, no barrier)
        bf16x8 ap = *(const bf16x8*)&pl[l15 * 40 + quad * 8];

        // PV: B[k=kv][n=dk]; lane holds VT[dk0+l15][kb + quad*8 + j]
#pragma unroll
        for (int t = 0; t < 4; ++t) {
            const u16* vptr = VT + ((size_t)bh * DK_ + t * 16 + l15) * T_ + kb + quad * 8;
            bf16x8 bv = *(const bf16x8*)vptr;
            o[t] = __builtin_amdgcn_mfma_f32_16x16x32_bf16(ap, bv, o[t], 0, 0, 0);
        }
    }

    // epilogue: O[row][dk] / l[row] -> ctx bf16 [B][T][D]
#pragma unroll
    for (int r = 0; r < 4; ++r) {
        const float inv = 1.0f / l[r];
        const int row = qb + quad * 4 + r;
        u16* cp = ctx + ((size_t)b * T_ + row) * D_ + h * DK_ + l15;
#pragma unroll
        for (int t = 0; t < 4; ++t) cp[t * 16] = f2bf_bits(o[t][r] * inv);
    }
}

extern "C" void kernel_launch(void* const* d_in, const int* in_sizes, int n_in,
                              void* d_out, int out_size, void* d_ws, size_t ws_size,
                              hipStream_t stream) {
    const float* query = (const float*)d_in[0];
    const float* key   = (const float*)d_in[1];
    const float* value = (const float*)d_in[2];
    // d_in[3] = alibi (unused: computed inline, bit-exact slopes)
    const float* Wq    = (const float*)d_in[4];
    const float* Wk    = (const float*)d_in[5];
    const float* Wv    = (const float*)d_in[6];
    const float* Wo    = (const float*)d_in[7];
    const float* bo    = (const float*)d_in[8];
    float* out = (float*)d_out;

    const size_t elems = (size_t)B_ * H_ * T_ * DK_;  // 4M
    u16* Qb   = (u16*)d_ws;
    u16* Kb   = Qb + elems;
    u16* VTb  = Kb + elems;
    u16* ctxb = VTb + elems;   // [B,T,D] bf16; 32 MB total

    dim3 gGemm(D_ / 64, M_ / 64);
    dim3 blk(256);

    gemm_xwt<float, 0><<<gGemm, blk, 0, stream>>>(query, Wq, nullptr, Qb,  nullptr, M_, D_, D_);
    gemm_xwt<float, 0><<<gGemm, blk, 0, stream>>>(key,   Wk, nullptr, Kb,  nullptr, M_, D_, D_);
    gemm_xwt<float, 2><<<gGemm, blk, 0, stream>>>(value, Wv, nullptr, VTb, nullptr, M_, D_, D_);

    dim3 gAttn(T_ / 64, B_ * H_);  // (32, 32)
    flash_attn<<<gAttn, blk, 0, stream>>>(Qb, Kb, VTb, ctxb);

    gemm_xwt<__hip_bfloat16, 1><<<gGemm, blk, 0, stream>>>((const __hip_bfloat16*)ctxb, Wo, bo, nullptr, out, M_, D_, D_);
}

// Round 4
// 612.697 us; speedup vs baseline: 7.3501x; 2.0130x over previous
//
#include <hip/hip_runtime.h>
#include <hip/hip_bf16.h>

// ALiBi MHA. B=2,T=2048,D=1024,H=16,DK=64. fp32 in/out.
// R4: all GEMMs on bf16 MFMA (128x128 tile, BK=32, fp32->bf16 convert in staging).
//     QKV fused in one dispatch (grid.z=3); V^T via LDS-transpose epilogue.
//     Flash attention unchanged core, longest-first dispatch order.

#define B_  2
#define T_  2048
#define D_  1024
#define H_  16
#define DK_ 64
#define M_  (B_ * T_)

typedef unsigned short u16;
typedef __attribute__((ext_vector_type(8))) short bf16x8;
typedef __attribute__((ext_vector_type(4))) float f32x4;

// slope_h = 2^(-(h+1)/2), double literals -> fp32 (bit-exact vs numpy)
__device__ __constant__ float d_slopes[16] = {
    0.70710678118654752440f, 0.5f, 0.35355339059327376220f, 0.25f,
    0.17677669529663688110f, 0.125f, 0.088388347648318440550f, 0.0625f,
    0.044194173824159220275f, 0.03125f, 0.022097086912079610137f, 0.015625f,
    0.011048543456039805068f, 0.0078125f, 0.0055242717280199025342f, 0.00390625f};

__device__ __forceinline__ u16 f2bf_bits(float v) {
    union { __hip_bfloat16 h; u16 u; } cv;
    cv.h = __float2bfloat16(v);
    return cv.u;
}

// ---- shared MFMA tile compute: 128x128 block tile, 4 waves in 2x2, BK=32 ----
// As/Bs: [128 rows][40 u16 stride] (row-major, k contiguous; 80B stride -> 2-way free)
__device__ __forceinline__ void mfma_step(const u16* As, const u16* Bs,
                                          int wm, int wn, int l15, int quad,
                                          f32x4 acc[4][4]) {
    bf16x8 af[4], bf[4];
#pragma unroll
    for (int mi = 0; mi < 4; ++mi)
        af[mi] = *(const bf16x8*)&As[(wm * 64 + mi * 16 + l15) * 40 + quad * 8];
#pragma unroll
    for (int ni = 0; ni < 4; ++ni)
        bf[ni] = *(const bf16x8*)&Bs[(wn * 64 + ni * 16 + l15) * 40 + quad * 8];
#pragma unroll
    for (int mi = 0; mi < 4; ++mi)
#pragma unroll
        for (int ni = 0; ni < 4; ++ni)
            acc[mi][ni] = __builtin_amdgcn_mfma_f32_16x16x32_bf16(af[mi], bf[ni], acc[mi][ni], 0, 0, 0);
}

// QKV projections, fused: blockIdx.z selects (X, W, out). C = X @ W^T.
// z=0 (Q), z=1 (K): bf16 out, split-head [bh][T][DK]
// z=2 (V): bf16 out, transposed [bh][DK][T] via LDS transpose
__global__ __launch_bounds__(256) void gemm_qkv(
    const float* __restrict__ xq, const float* __restrict__ xk, const float* __restrict__ xv,
    const float* __restrict__ wq, const float* __restrict__ wk, const float* __restrict__ wv,
    u16* __restrict__ oq, u16* __restrict__ ok, u16* __restrict__ ov) {
    __shared__ u16 smem[2 * 128 * 40];   // As|Bs (20480 B); reused as Cs (64x136) for V^T
    u16* As = smem;
    u16* Bs = smem + 128 * 40;

    const int z = blockIdx.z;
    const float* X = (z == 0) ? xq : (z == 1) ? xk : xv;
    const float* W = (z == 0) ? wq : (z == 1) ? wk : wv;

    const int tid = threadIdx.x;
    const int lane = tid & 63;
    const int l15 = lane & 15, quad = lane >> 4;
    const int wid = tid >> 6;
    const int wm = wid >> 1, wn = wid & 1;
    const int m0 = blockIdx.y * 128;
    const int n0 = blockIdx.x * 128;

    const int srow = tid >> 1;      // 0..127
    const int shalf = tid & 1;      // k-half (16 elems)
    const float* xp0 = X + (size_t)(m0 + srow) * D_ + shalf * 16;
    const float* wp0 = W + (size_t)(n0 + srow) * D_ + shalf * 16;
    u16* asw = As + srow * 40 + shalf * 16;
    u16* bsw = Bs + srow * 40 + shalf * 16;

    f32x4 acc[4][4];
#pragma unroll
    for (int mi = 0; mi < 4; ++mi)
#pragma unroll
        for (int ni = 0; ni < 4; ++ni) acc[mi][ni] = f32x4{0.f, 0.f, 0.f, 0.f};

    for (int k0 = 0; k0 < D_; k0 += 32) {
        alignas(16) u16 ta[16], tb[16];
#pragma unroll
        for (int i = 0; i < 4; ++i) {
            float4 f = *(const float4*)(xp0 + k0 + i * 4);
            ta[i * 4 + 0] = f2bf_bits(f.x); ta[i * 4 + 1] = f2bf_bits(f.y);
            ta[i * 4 + 2] = f2bf_bits(f.z); ta[i * 4 + 3] = f2bf_bits(f.w);
        }
#pragma unroll
        for (int i = 0; i < 4; ++i) {
            float4 f = *(const float4*)(wp0 + k0 + i * 4);
            tb[i * 4 + 0] = f2bf_bits(f.x); tb[i * 4 + 1] = f2bf_bits(f.y);
            tb[i * 4 + 2] = f2bf_bits(f.z); tb[i * 4 + 3] = f2bf_bits(f.w);
        }
        __syncthreads();
        *(uint4*)asw = *(const uint4*)&ta[0];
        *(uint4*)(asw + 8) = *(const uint4*)&ta[8];
        *(uint4*)bsw = *(const uint4*)&tb[0];
        *(uint4*)(bsw + 8) = *(const uint4*)&tb[8];
        __syncthreads();
        mfma_step(As, Bs, wm, wn, l15, quad, acc);
    }

    if (z < 2) {
        u16* out = (z == 0) ? oq : ok;
#pragma unroll
        for (int mi = 0; mi < 4; ++mi) {
            const int gmb = m0 + wm * 64 + mi * 16 + quad * 4;
#pragma unroll
            for (int ni = 0; ni < 4; ++ni) {
                const int gn = n0 + wn * 64 + ni * 16 + l15;
                const int h = gn >> 6, dk = gn & 63;
#pragma unroll
                for (int r = 0; r < 4; ++r) {
                    const int gm = gmb + r;
                    const int b = gm >> 11, t = gm & (T_ - 1);
                    out[(((size_t)b * H_ + h) * T_ + t) * DK_ + dk] = f2bf_bits(acc[mi][ni][r]);
                }
            }
        }
    } else {
        // V^T: stage 64 n-rows x 128 m into LDS (stride 136), copy out coalesced
        u16* Cs = smem;
#pragma unroll
        for (int h2 = 0; h2 < 2; ++h2) {
            __syncthreads();
            if (wn == h2) {
#pragma unroll
                for (int mi = 0; mi < 4; ++mi) {
#pragma unroll
                    for (int ni = 0; ni < 4; ++ni) {
                        const int nloc = ni * 16 + l15;
                        const int mloc = wm * 64 + mi * 16 + quad * 4;
                        alignas(8) u16 pk[4];
#pragma unroll
                        for (int r = 0; r < 4; ++r) pk[r] = f2bf_bits(acc[mi][ni][r]);
                        *(uint2*)&Cs[nloc * 136 + mloc] = *(const uint2*)pk;
                    }
                }
            }
            __syncthreads();
            const int nr = tid >> 2;
            const int mseg = (tid & 3) * 32;
            const int gn = n0 + h2 * 64 + nr;
            const int h = gn >> 6, dk = gn & 63;
            const int b = m0 >> 11;
            const int tl = (m0 & (T_ - 1)) + mseg;
            uint4 v0 = *(const uint4*)&Cs[nr * 136 + mseg];
            uint4 v1 = *(const uint4*)&Cs[nr * 136 + mseg + 8];
            uint4 v2 = *(const uint4*)&Cs[nr * 136 + mseg + 16];
            uint4 v3 = *(const uint4*)&Cs[nr * 136 + mseg + 24];
            u16* op = ov + ((size_t)(b * H_ + h) * DK_ + dk) * T_ + tl;
            *(uint4*)op = v0; *(uint4*)(op + 8) = v1;
            *(uint4*)(op + 16) = v2; *(uint4*)(op + 24) = v3;
        }
    }
}

// Output projection: out = ctx(bf16) @ Wo^T + bo, fp32 out [M,D]
__global__ __launch_bounds__(256) void gemm_out(const u16* __restrict__ X,
                                                const float* __restrict__ W,
                                                const float* __restrict__ bias,
                                                float* __restrict__ out) {
    __shared__ u16 As[128 * 40];
    __shared__ u16 Bs[128 * 40];

    const int tid = threadIdx.x;
    const int lane = tid & 63;
    const int l15 = lane & 15, quad = lane >> 4;
    const int wid = tid >> 6;
    const int wm = wid >> 1, wn = wid & 1;
    const int m0 = blockIdx.y * 128;
    const int n0 = blockIdx.x * 128;

    const int srow = tid >> 1;
    const int shalf = tid & 1;
    const u16* xp0 = X + (size_t)(m0 + srow) * D_ + shalf * 16;
    const float* wp0 = W + (size_t)(n0 + srow) * D_ + shalf * 16;
    u16* asw = As + srow * 40 + shalf * 16;
    u16* bsw = Bs + srow * 40 + shalf * 16;

    f32x4 acc[4][4];
#pragma unroll
    for (int mi = 0; mi < 4; ++mi)
#pragma unroll
        for (int ni = 0; ni < 4; ++ni) acc[mi][ni] = f32x4{0.f, 0.f, 0.f, 0.f};

    for (int k0 = 0; k0 < D_; k0 += 32) {
        uint4 xa = *(const uint4*)(xp0 + k0);
        uint4 xb = *(const uint4*)(xp0 + k0 + 8);
        alignas(16) u16 tb[16];
#pragma unroll
        for (int i = 0; i < 4; ++i) {
            float4 f = *(const float4*)(wp0 + k0 + i * 4);
            tb[i * 4 + 0] = f2bf_bits(f.x); tb[i * 4 + 1] = f2bf_bits(f.y);
            tb[i * 4 + 2] = f2bf_bits(f.z); tb[i * 4 + 3] = f2bf_bits(f.w);
        }
        __syncthreads();
        *(uint4*)asw = xa;
        *(uint4*)(asw + 8) = xb;
        *(uint4*)bsw = *(const uint4*)&tb[0];
        *(uint4*)(bsw + 8) = *(const uint4*)&tb[8];
        __syncthreads();
        mfma_step(As, Bs, wm, wn, l15, quad, acc);
    }

#pragma unroll
    for (int mi = 0; mi < 4; ++mi) {
        const int gmb = m0 + wm * 64 + mi * 16 + quad * 4;
#pragma unroll
        for (int ni = 0; ni < 4; ++ni) {
            const int gn = n0 + wn * 64 + ni * 16 + l15;
            const float bv = bias[gn];
#pragma unroll
            for (int r = 0; r < 4; ++r)
                out[(size_t)(gmb + r) * D_ + gn] = acc[mi][ni][r] + bv;
        }
    }
}

// Flash attention: 4 waves/block, wave handles 16 Q rows of one bh.
// Q,K: bf16 [bh][T][DK]; VT: bf16 [bh][DK][T]; ctx out: bf16 [B][T][D].
// Longest-first: qtile reversed so high-qb blocks dispatch first.
__global__ __launch_bounds__(256) void flash_attn(const u16* __restrict__ Q,
                                                  const u16* __restrict__ K,
                                                  const u16* __restrict__ VT,
                                                  u16* __restrict__ ctx) {
    const int bh = blockIdx.x;
    const int b  = bh >> 4;
    const int h  = bh & 15;
    const int wave = threadIdx.x >> 6;
    const int lane = threadIdx.x & 63;
    const int l15 = lane & 15;
    const int quad = lane >> 4;
    const int qt = gridDim.y - 1 - blockIdx.y;
    const int qb = qt * 64 + wave * 16;
    const float slope = d_slopes[h];

    __shared__ u16 plds[4][16 * 40];
    u16* pl = plds[wave];

    const size_t baseQK = (size_t)bh * T_ * DK_;
    const u16* qptr = Q + baseQK + (size_t)(qb + l15) * DK_ + quad * 8;
    bf16x8 aq0 = *(const bf16x8*)qptr;
    bf16x8 aq1 = *(const bf16x8*)(qptr + 32);

    f32x4 o[4];
    float m[4], l[4];
#pragma unroll
    for (int r = 0; r < 4; ++r) {
        o[r] = f32x4{0.f, 0.f, 0.f, 0.f};
        m[r] = -INFINITY;
        l[r] = 0.f;
    }

    const f32x4 zero = {0.f, 0.f, 0.f, 0.f};

    for (int kb = 0; kb <= qb + 15; kb += 32) {
        const u16* kptr = K + baseQK + (size_t)(kb + l15) * DK_ + quad * 8;
        bf16x8 bk00 = *(const bf16x8*)kptr;
        bf16x8 bk01 = *(const bf16x8*)(kptr + 32);
        bf16x8 bk10 = *(const bf16x8*)(kptr + 16 * DK_);
        bf16x8 bk11 = *(const bf16x8*)(kptr + 16 * DK_ + 32);

        f32x4 s0 = __builtin_amdgcn_mfma_f32_16x16x32_bf16(aq0, bk00, zero, 0, 0, 0);
        s0 = __builtin_amdgcn_mfma_f32_16x16x32_bf16(aq1, bk01, s0, 0, 0, 0);
        f32x4 s1 = __builtin_amdgcn_mfma_f32_16x16x32_bf16(aq0, bk10, zero, 0, 0, 0);
        s1 = __builtin_amdgcn_mfma_f32_16x16x32_bf16(aq1, bk11, s1, 0, 0, 0);

        float sc0[4], sc1[4];
#pragma unroll
        for (int r = 0; r < 4; ++r) {
            const int row = qb + quad * 4 + r;
            const int c0 = kb + l15;
            const int c1 = c0 + 16;
            float v0 = s0[r] * 0.125f + slope * (float)(c0 - row);
            float v1 = s1[r] * 0.125f + slope * (float)(c1 - row);
            sc0[r] = (c0 <= row) ? v0 : -INFINITY;
            sc1[r] = (c1 <= row) ? v1 : -INFINITY;
        }

        float alpha[4];
#pragma unroll
        for (int r = 0; r < 4; ++r) {
            float t = fmaxf(sc0[r], sc1[r]);
            t = fmaxf(t, __shfl_xor(t, 1));
            t = fmaxf(t, __shfl_xor(t, 2));
            t = fmaxf(t, __shfl_xor(t, 4));
            t = fmaxf(t, __shfl_xor(t, 8));
            const float mn = fmaxf(m[r], t);
            alpha[r] = __expf(m[r] - mn);
            m[r] = mn;
            const float p0 = __expf(sc0[r] - mn);
            const float p1 = __expf(sc1[r] - mn);
            pl[(quad * 4 + r) * 40 + l15]      = f2bf_bits(p0);
            pl[(quad * 4 + r) * 40 + l15 + 16] = f2bf_bits(p1);
            float s = p0 + p1;
            s += __shfl_xor(s, 1);
            s += __shfl_xor(s, 2);
            s += __shfl_xor(s, 4);
            s += __shfl_xor(s, 8);
            l[r] = l[r] * alpha[r] + s;
        }

#pragma unroll
        for (int t = 0; t < 4; ++t)
#pragma unroll
            for (int r = 0; r < 4; ++r) o[t][r] *= alpha[r];

        bf16x8 ap = *(const bf16x8*)&pl[l15 * 40 + quad * 8];

#pragma unroll
        for (int t = 0; t < 4; ++t) {
            const u16* vptr = VT + ((size_t)bh * DK_ + t * 16 + l15) * T_ + kb + quad * 8;
            bf16x8 bv = *(const bf16x8*)vptr;
            o[t] = __builtin_amdgcn_mfma_f32_16x16x32_bf16(ap, bv, o[t], 0, 0, 0);
        }
    }

#pragma unroll
    for (int r = 0; r < 4; ++r) {
        const float inv = 1.0f / l[r];
        const int row = qb + quad * 4 + r;
        u16* cp = ctx + ((size_t)b * T_ + row) * D_ + h * DK_ + l15;
#pragma unroll
        for (int t = 0; t < 4; ++t) cp[t * 16] = f2bf_bits(o[t][r] * inv);
    }
}

extern "C" void kernel_launch(void* const* d_in, const int* in_sizes, int n_in,
                              void* d_out, int out_size, void* d_ws, size_t ws_size,
                              hipStream_t stream) {
    const float* query = (const float*)d_in[0];
    const float* key   = (const float*)d_in[1];
    const float* value = (const float*)d_in[2];
    // d_in[3] = alibi (computed inline, bit-exact slopes)
    const float* Wq    = (const float*)d_in[4];
    const float* Wk    = (const float*)d_in[5];
    const float* Wv    = (const float*)d_in[6];
    const float* Wo    = (const float*)d_in[7];
    const float* bo    = (const float*)d_in[8];
    float* out = (float*)d_out;

    const size_t elems = (size_t)B_ * H_ * T_ * DK_;  // 4M
    u16* Qb   = (u16*)d_ws;
    u16* Kb   = Qb + elems;
    u16* VTb  = Kb + elems;
    u16* ctxb = VTb + elems;   // 32 MB total

    dim3 blk(256);
    gemm_qkv<<<dim3(D_ / 128, M_ / 128, 3), blk, 0, stream>>>(query, key, value, Wq, Wk, Wv, Qb, Kb, VTb);
    flash_attn<<<dim3(B_ * H_, T_ / 64), blk, 0, stream>>>(Qb, Kb, VTb, ctxb);
    gemm_out<<<dim3(D_ / 128, M_ / 128), blk, 0, stream>>>(ctxb, Wo, bo, out);
}